// Round 1
// 336.713 us; speedup vs baseline: 1.0481x; 1.0481x over previous
//
#include <hip/hip_runtime.h>

// Chain of 9 Linear layers, no activation => collapse to one affine map.
// dims: 784 -> 69 -> 31 -> 10 -> ... -> 10
//
// R7: fuse the two prep kernels into ONE (prep_all, 18 blocks x 512):
//   - every block redundantly computes the collapse chain S8 = W8*...*W1
//     in its own LDS (tiny: ~2-3us, runs in PARALLEL across blocks instead
//     of one whole-GPU-idle single-block kernel),
//   - then folds its 512-entry slice of Wt2 reading S from LOCAL LDS
//     (kills the S8 global round-trip),
//   - block 0 also emits beff.
//   Saves one kernel launch + one graph serialization point. linear_main
//   is UNCHANGED (R6 structure, ~HBM-floor ~35-40us per analysis; harness
//   fills at 122us/84% peak dominate the remaining dur_us).
//
// MAIN (R6): lane = (row, j-segment) — kills x divergence with NO transpose.
//   512-thr blocks, row = t>>3 (8 rows/wave), s = t&7 owns j = jb*32+s*4.
//   x loads coalesced (8 rows x 128B whole lines per instr). acc[10] per
//   lane; 3-step shfl_xor over the 8-lane row group; lanes s<5 write float2.
//   Weights in LDS, padded 11*float4 per j-quad: start bank quad (3s+o)&7
//   -> all 8 addr groups disjoint, 8-way broadcast: conflict-free.
//   Tail 784=24*32+16: weight j4 196..199 zeroed, x addr clamped to 780.
//   LDS 35.2KB -> 4 blocks/CU = 32 waves/CU (max). No atomics, 1 barrier.

// Wt2 layout: [200 j-quads][11 float4]; entry (j4, o<10) = {W[o][j4*4+k]}_{k=0..3}
// (composed weight); o==10 and j4 in [196,200) are zero padding.
__global__ void prep_all(
    const float* __restrict__ W0,
    const float* __restrict__ W1, const float* __restrict__ b1,
    const float* __restrict__ W2, const float* __restrict__ b2,
    const float* __restrict__ W3, const float* __restrict__ b3,
    const float* __restrict__ W4, const float* __restrict__ b4,
    const float* __restrict__ W5, const float* __restrict__ b5,
    const float* __restrict__ W6, const float* __restrict__ b6,
    const float* __restrict__ W7, const float* __restrict__ b7,
    const float* __restrict__ W8, const float* __restrict__ b8,
    const float* __restrict__ b0,
    float* __restrict__ Wt2, float* __restrict__ beff)
{
    __shared__ float Sa[31 * 69], Sb[31 * 69];
    __shared__ float da[31], db[31];
    const int t = threadIdx.x;
    const int nt = blockDim.x;

    // ---- collapse chain (redundant per block; identical FP order to R6) ----
    for (int i = t; i < 31 * 69; i += nt) Sa[i] = W1[i];
    for (int i = t; i < 31; i += nt) da[i] = b1[i];
    __syncthreads();

    for (int i = t; i < 10 * 69; i += nt) {
        int o = i / 69, c = i - o * 69;
        float s = 0.f;
        for (int k = 0; k < 31; k++) s += W2[o * 31 + k] * Sa[k * 69 + c];
        Sb[i] = s;
    }
    for (int i = t; i < 10; i += nt) {
        float s = b2[i];
        for (int k = 0; k < 31; k++) s += W2[i * 31 + k] * da[k];
        db[i] = s;
    }
    __syncthreads();

    const float* Wk[6] = { W3, W4, W5, W6, W7, W8 };
    const float* bk[6] = { b3, b4, b5, b6, b7, b8 };
    int src = 1;  // runtime ternaries: gfx950 rejects arrays of LDS pointers
    for (int st = 0; st < 6; st++) {
        const float* W = Wk[st];
        const float* bb = bk[st];
        float* S  = src ? Sb : Sa;
        float* D  = src ? Sa : Sb;
        float* dd = src ? db : da;
        float* dn = src ? da : db;
        for (int i = t; i < 10 * 69; i += nt) {
            int o = i / 69, c = i - o * 69;
            float s = 0.f;
            for (int k = 0; k < 10; k++) s += W[o * 10 + k] * S[k * 69 + c];
            D[i] = s;
        }
        for (int i = t; i < 10; i += nt) {
            float s = bb[i];
            for (int k = 0; k < 10; k++) s += W[i * 10 + k] * dd[k];
            dn[i] = s;
        }
        __syncthreads();
        src ^= 1;
    }

    float* S  = src ? Sb : Sa;   // src back to 1 after 6 flips -> Sb
    float* dd = src ? db : da;

    // ---- beff (block 0 only; same FP order as R6) ----
    if (blockIdx.x == 0) {
        for (int i = t; i < 10; i += nt) {
            float s = dd[i];
            for (int k = 0; k < 69; k++) s += S[i * 69 + k] * b0[k];
            beff[i] = s;
        }
    }

    // ---- fold slice: Wt2 entry per thread, S read from LOCAL LDS ----
    int e = blockIdx.x * nt + t;   // 0..9215, need 0..8799
    if (e < 8800) {
        int j4 = e / 44, rem = e - j4 * 44;
        float val = 0.f;
        if (rem < 40) {
            int o = rem >> 2, k = rem & 3, j = j4 * 4 + k;
            if (j < 784) {
                for (int u = 0; u < 69; u++) val += S[o * 69 + u] * W0[u * 784 + j];
            }
        }
        Wt2[e] = val;
    }
}

// ---- main (unchanged R6) ----

__global__ __launch_bounds__(512, 8) void linear_main(
    const float* __restrict__ x, const float* __restrict__ Wt2,
    const float* __restrict__ beff, float* __restrict__ out)
{
    __shared__ float4 wlds[2200];   // 35.2 KB
    const int t = threadIdx.x;
    const int s = t & 7;                         // j-segment within row group
    const long row = (long)blockIdx.x * 64 + (t >> 3);
    const float* xrow = x + row * 784;

    // stage weights (independent of the first x load)
    {
        const float4* wg = (const float4*)Wt2;
        for (int i = t; i < 2200; i += 512) wlds[i] = wg[i];
    }

    float acc[10];
#pragma unroll
    for (int o = 0; o < 10; o++) acc[o] = 0.f;

    // first x load issued before the barrier
    float4 xv = *(const float4*)(xrow + s * 4);
    __syncthreads();

    for (int jb = 0; jb < 25; jb++) {
        float4 xc = xv;
        if (jb < 24) {
            int jn = (jb + 1) * 32 + s * 4;
            jn = jn > 780 ? 780 : jn;            // clamp: tail cols have zero W
            xv = *(const float4*)(xrow + jn);
        }
        const float4* wrow = &wlds[(jb * 8 + s) * 11];
#pragma unroll
        for (int o = 0; o < 10; o++) {
            float4 wv = wrow[o];
            acc[o] = fmaf(xc.x, wv.x, acc[o]);
            acc[o] = fmaf(xc.y, wv.y, acc[o]);
            acc[o] = fmaf(xc.z, wv.z, acc[o]);
            acc[o] = fmaf(xc.w, wv.w, acc[o]);
        }
    }

    // butterfly sum over the 8 lanes sharing this row (bits 0..2 of lane id)
#pragma unroll
    for (int m = 1; m < 8; m <<= 1)
#pragma unroll
        for (int o = 0; o < 10; o++) acc[o] += __shfl_xor(acc[o], m, 64);

    // lanes s<5 write float2 (out + row*10 is 8B-aligned; 40B per row)
    if (s < 5) {
        float lo = 0.f, hi = 0.f;
#pragma unroll
        for (int o = 0; o < 5; o++) {
            if (s == o) { lo = acc[2 * o]; hi = acc[2 * o + 1]; }  // cndmask chain
        }
        lo += beff[s * 2];
        hi += beff[s * 2 + 1];
        *(float2*)(out + row * 10 + s * 2) = make_float2(lo, hi);
    }
}

extern "C" void kernel_launch(void* const* d_in, const int* in_sizes, int n_in,
                              void* d_out, int out_size, void* d_ws, size_t ws_size,
                              hipStream_t stream) {
    const float* x  = (const float*)d_in[0];
    const float* W0 = (const float*)d_in[1];
    const float* b0 = (const float*)d_in[2];
    const float* W1 = (const float*)d_in[3];
    const float* b1 = (const float*)d_in[4];
    const float* W2 = (const float*)d_in[5];
    const float* b2 = (const float*)d_in[6];
    const float* W3 = (const float*)d_in[7];
    const float* b3 = (const float*)d_in[8];
    const float* W4 = (const float*)d_in[9];
    const float* b4 = (const float*)d_in[10];
    const float* W5 = (const float*)d_in[11];
    const float* b5 = (const float*)d_in[12];
    const float* W6 = (const float*)d_in[13];
    const float* b6 = (const float*)d_in[14];
    const float* W7 = (const float*)d_in[15];
    const float* b7 = (const float*)d_in[16];
    const float* W8 = (const float*)d_in[17];
    const float* b8 = (const float*)d_in[18];

    float* ws   = (float*)d_ws;
    float* Wt2  = ws;            // 8800 floats: [200 j4][11 float4]
    float* beff = ws + 8800;     // 10 floats

    float* out = (float*)d_out;
    const int B = in_sizes[0] / 784;  // 65536

    prep_all<<<18, 512, 0, stream>>>(W0, W1, b1, W2, b2, W3, b3, W4, b4,
                                     W5, b5, W6, b6, W7, b7, W8, b8,
                                     b0, Wt2, beff);
    linear_main<<<B / 64, 512, 0, stream>>>(x, Wt2, beff, out);
}

// Round 2
// 335.866 us; speedup vs baseline: 1.0508x; 1.0025x over previous
//
#include <hip/hip_runtime.h>

// Chain of 9 Linear layers, no activation => collapse to one affine map.
// dims: 784 -> 69 -> 31 -> 10 -> ... -> 10
//
// R8: register-block 2 rows per lane in linear_main.
//   R6/R7 main was LDS-throughput-bound: 10 ds_read_b128 per 40 FMAs per
//   lane -> 8000 ds_read_b128/CU x ~12cyc = ~40us > x-stream HBM floor
//   (~29us). Now each lane owns rows (t>>3) and (t>>3)+64 of a 128-row
//   block: one weight read feeds 8 FMAs, per-CU LDS instrs halve (~20us),
//   kernel becomes HBM-bound on the x stream. 512 blocks, 2 blocks/CU,
//   16 waves/CU; per-row FP order identical to R6 (absmax unchanged).
//
// prep_all (R7): 18 blocks x 512; every block redundantly computes the
//   collapse chain S8 = W8*...*W1 in its own LDS, folds its 512-entry
//   slice of Wt2 from LOCAL LDS; block 0 emits beff. One launch, no S8
//   global round-trip.
//
// MAIN lane layout: s = t&7 owns j = jb*32+s*4; x loads coalesced
//   (8 rows x 128B whole lines per instr, x2 row sets). Weights in LDS,
//   padded 11*float4 per j-quad: start bank quad (3s+o)&7 -> all 8 addr
//   groups disjoint, 8-way broadcast: conflict-free. Tail 784=24*32+16:
//   weight j4 196..199 zeroed, x addr clamped to 780. 3-step shfl_xor
//   over the 8-lane row group; lanes s<5 write float2 per row.

// Wt2 layout: [200 j-quads][11 float4]; entry (j4, o<10) = {W[o][j4*4+k]}_{k=0..3}
// (composed weight); o==10 and j4 in [196,200) are zero padding.
__global__ void prep_all(
    const float* __restrict__ W0,
    const float* __restrict__ W1, const float* __restrict__ b1,
    const float* __restrict__ W2, const float* __restrict__ b2,
    const float* __restrict__ W3, const float* __restrict__ b3,
    const float* __restrict__ W4, const float* __restrict__ b4,
    const float* __restrict__ W5, const float* __restrict__ b5,
    const float* __restrict__ W6, const float* __restrict__ b6,
    const float* __restrict__ W7, const float* __restrict__ b7,
    const float* __restrict__ W8, const float* __restrict__ b8,
    const float* __restrict__ b0,
    float* __restrict__ Wt2, float* __restrict__ beff)
{
    __shared__ float Sa[31 * 69], Sb[31 * 69];
    __shared__ float da[31], db[31];
    const int t = threadIdx.x;
    const int nt = blockDim.x;

    // ---- collapse chain (redundant per block; identical FP order to R6) ----
    for (int i = t; i < 31 * 69; i += nt) Sa[i] = W1[i];
    for (int i = t; i < 31; i += nt) da[i] = b1[i];
    __syncthreads();

    for (int i = t; i < 10 * 69; i += nt) {
        int o = i / 69, c = i - o * 69;
        float s = 0.f;
        for (int k = 0; k < 31; k++) s += W2[o * 31 + k] * Sa[k * 69 + c];
        Sb[i] = s;
    }
    for (int i = t; i < 10; i += nt) {
        float s = b2[i];
        for (int k = 0; k < 31; k++) s += W2[i * 31 + k] * da[k];
        db[i] = s;
    }
    __syncthreads();

    const float* Wk[6] = { W3, W4, W5, W6, W7, W8 };
    const float* bk[6] = { b3, b4, b5, b6, b7, b8 };
    int src = 1;  // runtime ternaries: gfx950 rejects arrays of LDS pointers
    for (int st = 0; st < 6; st++) {
        const float* W = Wk[st];
        const float* bb = bk[st];
        float* S  = src ? Sb : Sa;
        float* D  = src ? Sa : Sb;
        float* dd = src ? db : da;
        float* dn = src ? da : db;
        for (int i = t; i < 10 * 69; i += nt) {
            int o = i / 69, c = i - o * 69;
            float s = 0.f;
            for (int k = 0; k < 10; k++) s += W[o * 10 + k] * S[k * 69 + c];
            D[i] = s;
        }
        for (int i = t; i < 10; i += nt) {
            float s = bb[i];
            for (int k = 0; k < 10; k++) s += W[i * 10 + k] * dd[k];
            dn[i] = s;
        }
        __syncthreads();
        src ^= 1;
    }

    float* S  = src ? Sb : Sa;   // src back to 1 after 6 flips -> Sb
    float* dd = src ? db : da;

    // ---- beff (block 0 only; same FP order as R6) ----
    if (blockIdx.x == 0) {
        for (int i = t; i < 10; i += nt) {
            float s = dd[i];
            for (int k = 0; k < 69; k++) s += S[i * 69 + k] * b0[k];
            beff[i] = s;
        }
    }

    // ---- fold slice: Wt2 entry per thread, S read from LOCAL LDS ----
    int e = blockIdx.x * nt + t;   // 0..9215, need 0..8799
    if (e < 8800) {
        int j4 = e / 44, rem = e - j4 * 44;
        float val = 0.f;
        if (rem < 40) {
            int o = rem >> 2, k = rem & 3, j = j4 * 4 + k;
            if (j < 784) {
                for (int u = 0; u < 69; u++) val += S[o * 69 + u] * W0[u * 784 + j];
            }
        }
        Wt2[e] = val;
    }
}

// ---- main (R8: 2 rows per lane) ----

__global__ __launch_bounds__(512, 4) void linear_main(
    const float* __restrict__ x, const float* __restrict__ Wt2,
    const float* __restrict__ beff, float* __restrict__ out)
{
    __shared__ float4 wlds[2200];   // 35.2 KB
    const int t = threadIdx.x;
    const int s = t & 7;                         // j-segment within row group
    const long row0 = (long)blockIdx.x * 128 + (t >> 3);   // second row = row0+64
    const float* xr0 = x + row0 * 784;
    const float* xr1 = xr0 + (long)64 * 784;

    // stage weights (independent of the first x loads)
    {
        const float4* wg = (const float4*)Wt2;
        for (int i = t; i < 2200; i += 512) wlds[i] = wg[i];
    }

    float acc0[10], acc1[10];
#pragma unroll
    for (int o = 0; o < 10; o++) { acc0[o] = 0.f; acc1[o] = 0.f; }

    // first x loads issued before the barrier
    float4 xv0 = *(const float4*)(xr0 + s * 4);
    float4 xv1 = *(const float4*)(xr1 + s * 4);
    __syncthreads();

    for (int jb = 0; jb < 25; jb++) {
        float4 xc0 = xv0, xc1 = xv1;
        if (jb < 24) {
            int jn = (jb + 1) * 32 + s * 4;
            jn = jn > 780 ? 780 : jn;            // clamp: tail cols have zero W
            xv0 = *(const float4*)(xr0 + jn);
            xv1 = *(const float4*)(xr1 + jn);
        }
        const float4* wrow = &wlds[(jb * 8 + s) * 11];
#pragma unroll
        for (int o = 0; o < 10; o++) {
            float4 wv = wrow[o];
            acc0[o] = fmaf(xc0.x, wv.x, acc0[o]);
            acc0[o] = fmaf(xc0.y, wv.y, acc0[o]);
            acc0[o] = fmaf(xc0.z, wv.z, acc0[o]);
            acc0[o] = fmaf(xc0.w, wv.w, acc0[o]);
            acc1[o] = fmaf(xc1.x, wv.x, acc1[o]);
            acc1[o] = fmaf(xc1.y, wv.y, acc1[o]);
            acc1[o] = fmaf(xc1.z, wv.z, acc1[o]);
            acc1[o] = fmaf(xc1.w, wv.w, acc1[o]);
        }
    }

    // butterfly sum over the 8 lanes sharing each row (bits 0..2 of lane id)
#pragma unroll
    for (int m = 1; m < 8; m <<= 1)
#pragma unroll
        for (int o = 0; o < 10; o++) {
            acc0[o] += __shfl_xor(acc0[o], m, 64);
            acc1[o] += __shfl_xor(acc1[o], m, 64);
        }

    // lanes s<5 write float2 per row (out + row*10 is 8B-aligned; 40B per row)
    if (s < 5) {
        float lo0 = 0.f, hi0 = 0.f, lo1 = 0.f, hi1 = 0.f;
#pragma unroll
        for (int o = 0; o < 5; o++) {
            if (s == o) {                         // cndmask chain
                lo0 = acc0[2 * o]; hi0 = acc0[2 * o + 1];
                lo1 = acc1[2 * o]; hi1 = acc1[2 * o + 1];
            }
        }
        float be0 = beff[s * 2], be1 = beff[s * 2 + 1];
        *(float2*)(out + row0 * 10 + s * 2) = make_float2(lo0 + be0, hi0 + be1);
        *(float2*)(out + (row0 + 64) * 10 + s * 2) = make_float2(lo1 + be0, hi1 + be1);
    }
}

extern "C" void kernel_launch(void* const* d_in, const int* in_sizes, int n_in,
                              void* d_out, int out_size, void* d_ws, size_t ws_size,
                              hipStream_t stream) {
    const float* x  = (const float*)d_in[0];
    const float* W0 = (const float*)d_in[1];
    const float* b0 = (const float*)d_in[2];
    const float* W1 = (const float*)d_in[3];
    const float* b1 = (const float*)d_in[4];
    const float* W2 = (const float*)d_in[5];
    const float* b2 = (const float*)d_in[6];
    const float* W3 = (const float*)d_in[7];
    const float* b3 = (const float*)d_in[8];
    const float* W4 = (const float*)d_in[9];
    const float* b4 = (const float*)d_in[10];
    const float* W5 = (const float*)d_in[11];
    const float* b5 = (const float*)d_in[12];
    const float* W6 = (const float*)d_in[13];
    const float* b6 = (const float*)d_in[14];
    const float* W7 = (const float*)d_in[15];
    const float* b7 = (const float*)d_in[16];
    const float* W8 = (const float*)d_in[17];
    const float* b8 = (const float*)d_in[18];

    float* ws   = (float*)d_ws;
    float* Wt2  = ws;            // 8800 floats: [200 j4][11 float4]
    float* beff = ws + 8800;     // 10 floats

    float* out = (float*)d_out;
    const int B = in_sizes[0] / 784;  // 65536

    prep_all<<<18, 512, 0, stream>>>(W0, W1, b1, W2, b2, W3, b3, W4, b4,
                                     W5, b5, W6, b6, W7, b7, W8, b8,
                                     b0, Wt2, beff);
    linear_main<<<B / 128, 512, 0, stream>>>(x, Wt2, beff, out);
}